// Round 1
// baseline (1192.922 us; speedup 1.0000x reference)
//
#include <hip/hip_runtime.h>
#include <cmath>

#define NTOK 8000          // B*NQ*NP
#define LV_TOT 17821

// ---------------- elementwise add (float4) ----------------
__global__ __launch_bounds__(256) void add_kernel(const float* __restrict__ a,
                                                  const float* __restrict__ b,
                                                  float* __restrict__ o, int n4) {
  int i = blockIdx.x * 256 + threadIdx.x;
  if (i < n4) {
    float4 x = reinterpret_cast<const float4*>(a)[i];
    float4 y = reinterpret_cast<const float4*>(b)[i];
    float4 z; z.x = x.x + y.x; z.y = x.y + y.y; z.z = x.z + y.z; z.w = x.w + y.w;
    reinterpret_cast<float4*>(o)[i] = z;
  }
}

// ---------------- generic GEMM: C[M,N] = A[M,K] @ W[N,K]^T + bias, opt ReLU ----------------
__global__ __launch_bounds__(256) void gemm_bias_kernel(
    const float* __restrict__ A, const float* __restrict__ W,
    const float* __restrict__ bias, float* __restrict__ C,
    int M, int N, int K, int relu)
{
  __shared__ float As[16][68];
  __shared__ float Ws[16][68];
  const int tid = threadIdx.x;
  const int r  = tid >> 2;          // 0..63
  const int c4 = (tid & 3) << 2;    // 0,4,8,12
  const int tx = tid & 15, ty = tid >> 4;
  const int arow = blockIdx.y * 64 + r;
  const int wrow = blockIdx.x * 64 + r;
  float acc[4][4] = {};
  for (int k0 = 0; k0 < K; k0 += 16) {
    float4 av = make_float4(0.f, 0.f, 0.f, 0.f);
    if (arow < M) av = *reinterpret_cast<const float4*>(A + (size_t)arow * K + k0 + c4);
    float4 wv = *reinterpret_cast<const float4*>(W + (size_t)wrow * K + k0 + c4);
    __syncthreads();
    As[c4+0][r] = av.x; As[c4+1][r] = av.y; As[c4+2][r] = av.z; As[c4+3][r] = av.w;
    Ws[c4+0][r] = wv.x; Ws[c4+1][r] = wv.y; Ws[c4+2][r] = wv.z; Ws[c4+3][r] = wv.w;
    __syncthreads();
    #pragma unroll
    for (int kk = 0; kk < 16; ++kk) {
      float a0 = As[kk][ty*4+0], a1 = As[kk][ty*4+1], a2 = As[kk][ty*4+2], a3 = As[kk][ty*4+3];
      float b0 = Ws[kk][tx*4+0], b1 = Ws[kk][tx*4+1], b2 = Ws[kk][tx*4+2], b3 = Ws[kk][tx*4+3];
      acc[0][0] += a0*b0; acc[0][1] += a0*b1; acc[0][2] += a0*b2; acc[0][3] += a0*b3;
      acc[1][0] += a1*b0; acc[1][1] += a1*b1; acc[1][2] += a1*b2; acc[1][3] += a1*b3;
      acc[2][0] += a2*b0; acc[2][1] += a2*b1; acc[2][2] += a2*b2; acc[2][3] += a2*b3;
      acc[3][0] += a3*b0; acc[3][1] += a3*b1; acc[3][2] += a3*b2; acc[3][3] += a3*b3;
    }
  }
  const int col = blockIdx.x * 64 + tx * 4;
  float4 bv = *reinterpret_cast<const float4*>(bias + col);
  #pragma unroll
  for (int i = 0; i < 4; ++i) {
    int row = blockIdx.y * 64 + ty * 4 + i;
    if (row < M) {
      float4 o;
      o.x = acc[i][0] + bv.x; o.y = acc[i][1] + bv.y;
      o.z = acc[i][2] + bv.z; o.w = acc[i][3] + bv.w;
      if (relu) {
        o.x = fmaxf(o.x, 0.f); o.y = fmaxf(o.y, 0.f);
        o.z = fmaxf(o.z, 0.f); o.w = fmaxf(o.w, 0.f);
      }
      *reinterpret_cast<float4*>(C + (size_t)row * N + col) = o;
    }
  }
}

// ---------------- LayerNorm: out = [x3 +] LN(x1 [+ x2]) * g + b ----------------
__global__ __launch_bounds__(256) void ln_kernel(const float* __restrict__ x1,
    const float* __restrict__ x2, const float* __restrict__ x3,
    const float* __restrict__ g, const float* __restrict__ bta,
    float* __restrict__ out)
{
  int wid = threadIdx.x >> 6, lane = threadIdx.x & 63;
  size_t t = (size_t)blockIdx.x * 4 + wid;
  size_t base = t * 256 + (size_t)lane * 4;
  float4 v = *reinterpret_cast<const float4*>(x1 + base);
  if (x2) {
    float4 u = *reinterpret_cast<const float4*>(x2 + base);
    v.x += u.x; v.y += u.y; v.z += u.z; v.w += u.w;
  }
  float s  = v.x + v.y + v.z + v.w;
  float ss = v.x*v.x + v.y*v.y + v.z*v.z + v.w*v.w;
  #pragma unroll
  for (int off = 32; off; off >>= 1) {
    s  += __shfl_xor(s, off, 64);
    ss += __shfl_xor(ss, off, 64);
  }
  float mean = s * (1.0f / 256.0f);
  float var  = ss * (1.0f / 256.0f) - mean * mean;
  float rstd = rsqrtf(var + 1e-5f);
  float4 gv = *reinterpret_cast<const float4*>(g + lane * 4);
  float4 bv = *reinterpret_cast<const float4*>(bta + lane * 4);
  float4 o;
  o.x = (v.x - mean) * rstd * gv.x + bv.x;
  o.y = (v.y - mean) * rstd * gv.y + bv.y;
  o.z = (v.z - mean) * rstd * gv.z + bv.z;
  o.w = (v.w - mean) * rstd * gv.w + bv.w;
  if (x3) {
    float4 u = *reinterpret_cast<const float4*>(x3 + base);
    o.x += u.x; o.y += u.y; o.z += u.z; o.w += u.w;
  }
  *reinterpret_cast<float4*>(out + base) = o;
}

// ---------------- transpose conv weight [256][256][9] -> [2304][256] ----------------
__global__ __launch_bounds__(256) void wt_kernel(const float* __restrict__ w,
                                                 float* __restrict__ wT) {
  int i = blockIdx.x * 256 + threadIdx.x;   // total 2304*256
  int ck = i >> 8;          // c*9+k
  int o  = i & 255;
  wT[i] = w[(size_t)o * 2304 + ck];
}

// ---------------- circular conv1d(k=9) + BN(eval) + ReLU, per sequence ----------------
__global__ __launch_bounds__(256) void conv_bn_kernel(
    const float* __restrict__ x,  const float* __restrict__ wT,
    const float* __restrict__ cb, const float* __restrict__ bng,
    const float* __restrict__ bnb, const float* __restrict__ bnm,
    const float* __restrict__ bnv, float* __restrict__ out)
{
  __shared__ float xs[28][256];
  int seq = blockIdx.x;                 // 0..399 = (b,nq)
  int t0 = seq * 20;
  int o = threadIdx.x;
  #pragma unroll
  for (int j = 0; j < 28; ++j) {
    int np = (j + 16) % 20;             // original position (j-4) mod 20
    xs[j][o] = x[(size_t)(t0 + np) * 256 + o];
  }
  __syncthreads();
  float acc[20] = {};
  for (int c = 0; c < 256; ++c) {
    float xv[28];
    #pragma unroll
    for (int j = 0; j < 28; ++j) xv[j] = xs[j][c];
    #pragma unroll
    for (int k = 0; k < 9; ++k) {
      float wv = wT[(size_t)(c * 9 + k) * 256 + o];
      #pragma unroll
      for (int np = 0; np < 20; ++np) acc[np] += xv[np + k] * wv;
    }
  }
  float scale = bng[o] * rsqrtf(bnv[o] + 1e-5f);
  float shift = (cb[o] - bnm[o]) * scale + bnb[o];
  #pragma unroll
  for (int np = 0; np < 20; ++np) {
    float v = acc[np] * scale + shift;
    out[(size_t)(t0 + np) * 256 + o] = fmaxf(v, 0.f);
  }
}

// ---------------- intra attention: 400 seqs of S=20, H=8, DH=32 ----------------
__global__ __launch_bounds__(256) void attn_intra_kernel(
    const float* __restrict__ qp, const float* __restrict__ kp,
    const float* __restrict__ vp, float* __restrict__ outb)
{
  __shared__ float Qs[20][257], Ks[20][257], Vs[20][257];
  int seq = blockIdx.x, t0 = seq * 20;
  for (int idx = threadIdx.x; idx < 20 * 256; idx += 256) {
    int r = idx >> 8, d = idx & 255;
    size_t g = (size_t)(t0 + r) * 256 + d;
    Qs[r][d] = qp[g]; Ks[r][d] = kp[g]; Vs[r][d] = vp[g];
  }
  __syncthreads();
  int h = threadIdx.x >> 5, i = threadIdx.x & 31;
  if (i < 20) {
    const float scale = 0.17677669529663687f;   // 1/sqrt(32)
    float s[20]; float m = -1e30f;
    #pragma unroll
    for (int j = 0; j < 20; ++j) {
      float a = 0.f;
      #pragma unroll
      for (int d = 0; d < 32; ++d) a += Qs[i][h*32+d] * Ks[j][h*32+d];
      a *= scale; s[j] = a; m = fmaxf(m, a);
    }
    float sum = 0.f;
    #pragma unroll
    for (int j = 0; j < 20; ++j) { s[j] = expf(s[j] - m); sum += s[j]; }
    float inv = 1.f / sum;
    #pragma unroll
    for (int d = 0; d < 32; ++d) {
      float o = 0.f;
      #pragma unroll
      for (int j = 0; j < 20; ++j) o += s[j] * Vs[j][h*32+d];
      outb[(size_t)(t0 + i) * 256 + h*32 + d] = o * inv;
    }
  }
}

// ---------------- inter attention: 80 seqs of S=100 (over nq), per (b,np,h) block ----------------
__global__ __launch_bounds__(128) void attn_inter_kernel(
    const float* __restrict__ qp, const float* __restrict__ kp,
    const float* __restrict__ vp, float* __restrict__ outb)
{
  __shared__ float Ks[100][32], Vs[100][32];
  int blk = blockIdx.x;                 // 0..639
  int h = blk & 7; int sp = blk >> 3; int np = sp % 20; int b = sp / 20;
  for (int idx = threadIdx.x; idx < 100 * 32; idx += 128) {
    int r = idx >> 5, d = idx & 31;
    size_t g = ((size_t)((b * 100 + r) * 20 + np)) * 256 + h*32 + d;
    Ks[r][d] = kp[g]; Vs[r][d] = vp[g];
  }
  __syncthreads();
  int i = threadIdx.x;
  if (i < 100) {
    size_t qbase = ((size_t)((b * 100 + i) * 20 + np)) * 256 + h*32;
    float q[32];
    #pragma unroll
    for (int d4 = 0; d4 < 8; ++d4) {
      float4 v = *reinterpret_cast<const float4*>(qp + qbase + d4*4);
      q[d4*4+0] = v.x; q[d4*4+1] = v.y; q[d4*4+2] = v.z; q[d4*4+3] = v.w;
    }
    const float scale = 0.17677669529663687f;
    float m = -1e30f, l = 0.f, o[32] = {};
    for (int j = 0; j < 100; ++j) {
      float s = 0.f;
      #pragma unroll
      for (int d = 0; d < 32; ++d) s += q[d] * Ks[j][d];
      s *= scale;
      float mn = fmaxf(m, s);
      float f = expf(m - mn), e = expf(s - mn);
      l = l * f + e;
      #pragma unroll
      for (int d = 0; d < 32; ++d) o[d] = o[d] * f + e * Vs[j][d];
      m = mn;
    }
    float inv = 1.f / l;
    #pragma unroll
    for (int d = 0; d < 32; ++d) outb[qbase + d] = o[d] * inv;
  }
}

// ---------------- deformable sampling (softmax over 16 + bilinear gather) ----------------
__global__ __launch_bounds__(256) void deform_kernel(
    const float* __restrict__ value, const float* __restrict__ offs,
    const float* __restrict__ awl, const float* __restrict__ ref,
    float* __restrict__ outb)
{
  int t = blockIdx.x;                       // 0..7999
  int h = threadIdx.x >> 5, dh = threadIdx.x & 31;
  int b = t / 2000;                         // NQ*NP
  float w[16]; float m = -1e30f;
  #pragma unroll
  for (int lp = 0; lp < 16; ++lp) {
    w[lp] = awl[(size_t)t * 128 + h * 16 + lp];
    m = fmaxf(m, w[lp]);
  }
  float sum = 0.f;
  #pragma unroll
  for (int lp = 0; lp < 16; ++lp) { w[lp] = expf(w[lp] - m); sum += w[lp]; }
  float inv = 1.f / sum;
  const int HLs[4] = {100, 50, 25, 13};
  const int WLs[4] = {134, 67, 34, 17};
  const int STs[4] = {0, 13400, 16750, 17600};
  float acc = 0.f;
  #pragma unroll
  for (int l = 0; l < 4; ++l) {
    const int Hl = HLs[l], Wl = WLs[l];
    const float* vb = value + ((size_t)(b * LV_TOT + STs[l])) * 256 + h*32 + dh;
    float rx = ref[(size_t)t * 8 + l * 2 + 0];
    float ry = ref[(size_t)t * 8 + l * 2 + 1];
    #pragma unroll
    for (int p = 0; p < 4; ++p) {
      size_t oi = (size_t)t * 256 + (size_t)(((h*4 + l)*4 + p)*2);
      float ox = offs[oi], oy = offs[oi + 1];
      // match reference: loc = ref + off/(W,H); x = loc*W - 0.5
      float x = (rx + ox / (float)Wl) * (float)Wl - 0.5f;
      float y = (ry + oy / (float)Hl) * (float)Hl - 0.5f;
      float x0f = floorf(x), y0f = floorf(y);
      float lx = x - x0f, ly = y - y0f;
      int x0 = (int)x0f, y0 = (int)y0f;
      float wp = w[l*4 + p] * inv;
      float cw00 = (1.f-lx)*(1.f-ly)*wp, cw01 = lx*(1.f-ly)*wp;
      float cw10 = (1.f-lx)*ly*wp,       cw11 = lx*ly*wp;
      if (y0 >= 0 && y0 < Hl) {
        if (x0 >= 0 && x0 < Wl)         acc += cw00 * vb[(size_t)(y0*Wl + x0) * 256];
        if (x0+1 >= 0 && x0+1 < Wl)     acc += cw01 * vb[(size_t)(y0*Wl + x0+1) * 256];
      }
      if (y0+1 >= 0 && y0+1 < Hl) {
        if (x0 >= 0 && x0 < Wl)         acc += cw10 * vb[(size_t)((y0+1)*Wl + x0) * 256];
        if (x0+1 >= 0 && x0+1 < Wl)     acc += cw11 * vb[(size_t)((y0+1)*Wl + x0+1) * 256];
      }
    }
  }
  outb[(size_t)t * 256 + h*32 + dh] = acc;
}

extern "C" void kernel_launch(void* const* d_in, const int* in_sizes, int n_in,
                              void* d_out, int out_size, void* d_ws, size_t ws_size,
                              hipStream_t stream)
{
  const float* tgt  = (const float*)d_in[0];
  const float* qpos = (const float*)d_in[1];
  const float* qpa  = (const float*)d_in[2];
  const float* ref  = (const float*)d_in[3];
  const float* src  = (const float*)d_in[4];
  const float* ia_wi = (const float*)d_in[7];
  const float* ia_bi = (const float*)d_in[8];
  const float* ia_wo = (const float*)d_in[9];
  const float* ia_bo = (const float*)d_in[10];
  const float* cc_w  = (const float*)d_in[11];
  const float* cc_b  = (const float*)d_in[12];
  const float* bn_g  = (const float*)d_in[13];
  const float* bn_b  = (const float*)d_in[14];
  const float* bn_m  = (const float*)d_in[15];
  const float* bn_v  = (const float*)d_in[16];
  const float* ni_g  = (const float*)d_in[17];
  const float* ni_b  = (const float*)d_in[18];
  const float* mf_w  = (const float*)d_in[19];
  const float* mf_b  = (const float*)d_in[20];
  const float* nf_g  = (const float*)d_in[21];
  const float* nf_b  = (const float*)d_in[22];
  const float* in_wi = (const float*)d_in[23];
  const float* in_bi = (const float*)d_in[24];
  const float* in_wo = (const float*)d_in[25];
  const float* in_bo = (const float*)d_in[26];
  const float* nin_g = (const float*)d_in[27];
  const float* nin_b = (const float*)d_in[28];
  const float* so_w  = (const float*)d_in[29];
  const float* so_b  = (const float*)d_in[30];
  const float* aw_w  = (const float*)d_in[31];
  const float* aw_b  = (const float*)d_in[32];
  const float* vp_w  = (const float*)d_in[33];
  const float* vp_b  = (const float*)d_in[34];
  const float* op_w  = (const float*)d_in[35];
  const float* op_b  = (const float*)d_in[36];
  const float* nc_g  = (const float*)d_in[37];
  const float* nc_b  = (const float*)d_in[38];
  const float* l1_w  = (const float*)d_in[39];
  const float* l1_b  = (const float*)d_in[40];
  const float* l2_w  = (const float*)d_in[41];
  const float* l2_b  = (const float*)d_in[42];
  const float* n3_g  = (const float*)d_in[43];
  const float* n3_b  = (const float*)d_in[44];
  float* out = (float*)d_out;

  float* ws = (float*)d_ws;
  const size_t TD = (size_t)NTOK * 256;
  float* A   = ws;
  float* Bb  = ws + TD;
  float* Cc  = ws + 2*TD;
  float* Dd  = ws + 3*TD;
  float* Ee  = ws + 4*TD;
  float* V   = ws + 5*TD;                     // 71284*256
  float* cwT = V + (size_t)71284 * 256;       // 2304*256
  float* Hbuf = V;                            // FFN hidden aliases V (value dead by then)

  dim3 blk(256);
  const int N4 = (int)(TD / 4);

  auto GEMM = [&](const float* Ain, const float* Win, const float* bin, float* Cout,
                  int M, int N, int K, int relu) {
    dim3 g(N / 64, (M + 63) / 64);
    hipLaunchKernelGGL(gemm_bias_kernel, g, blk, 0, stream, Ain, Win, bin, Cout, M, N, K, relu);
  };

  // ---- intra attention ----
  hipLaunchKernelGGL(add_kernel, dim3(2000), blk, 0, stream, tgt, qpos, A, N4);   // q = tgt+pos
  GEMM(A,   ia_wi,             ia_bi,       Bb, NTOK, 256, 256, 0);               // qp
  GEMM(A,   ia_wi + 256*256,   ia_bi + 256, Cc, NTOK, 256, 256, 0);               // kp
  GEMM(tgt, ia_wi + 512*256,   ia_bi + 512, Dd, NTOK, 256, 256, 0);               // vp (value=tgt!)
  hipLaunchKernelGGL(attn_intra_kernel, dim3(400), blk, 0, stream, Bb, Cc, Dd, Ee);
  GEMM(Ee,  ia_wo, ia_bo, Bb, NTOK, 256, 256, 0);                                 // t

  // ---- circular conv + BN + ReLU on (tgt+pos) ----
  hipLaunchKernelGGL(wt_kernel, dim3(2304), blk, 0, stream, cc_w, cwT);
  hipLaunchKernelGGL(conv_bn_kernel, dim3(400), blk, 0, stream,
                     A, cwT, cc_b, bn_g, bn_b, bn_m, bn_v, Cc);                   // t_cc

  // tgt1 = tgt + LN(t + t_cc)
  hipLaunchKernelGGL(ln_kernel, dim3(2000), blk, 0, stream, Bb, Cc, tgt, ni_g, ni_b, Dd);
  // tgt2 = tgt1 + LN(tgt1 @ mf)
  GEMM(Dd, mf_w, mf_b, A, NTOK, 256, 256, 0);
  hipLaunchKernelGGL(ln_kernel, dim3(2000), blk, 0, stream, A, (const float*)nullptr, Dd, nf_g, nf_b, Bb);

  // ---- inter attention (sequences over nq, per (b,np)) ----
  hipLaunchKernelGGL(add_kernel, dim3(2000), blk, 0, stream, Bb, qpa, A, N4);     // q2 = tgt2+anchor
  GEMM(A,  in_wi,           in_bi,       Cc, NTOK, 256, 256, 0);                  // qp2
  GEMM(A,  in_wi + 256*256, in_bi + 256, Dd, NTOK, 256, 256, 0);                  // kp2
  GEMM(Bb, in_wi + 512*256, in_bi + 512, Ee, NTOK, 256, 256, 0);                  // vp2 (value=tgt2)
  hipLaunchKernelGGL(attn_inter_kernel, dim3(640), dim3(128), 0, stream, Cc, Dd, Ee, A);
  GEMM(A, in_wo, in_bo, Cc, NTOK, 256, 256, 0);                                   // t2
  // tgt3 = LN(tgt2 + t2)
  hipLaunchKernelGGL(ln_kernel, dim3(2000), blk, 0, stream, Bb, Cc, (const float*)nullptr, nin_g, nin_b, Dd);

  // ---- deformable cross-attention ----
  hipLaunchKernelGGL(add_kernel, dim3(2000), blk, 0, stream, Dd, qpos, A, N4);    // qc = tgt3+pos
  GEMM(src, vp_w, vp_b, V, 4 * LV_TOT, 256, 256, 0);                              // value
  GEMM(A, so_w, so_b, Bb, NTOK, 256, 256, 0);                                     // offsets
  GEMM(A, aw_w, aw_b, Cc, NTOK, 128, 256, 0);                                     // aw logits
  hipLaunchKernelGGL(deform_kernel, dim3(NTOK), blk, 0, stream, V, Bb, Cc, ref, Ee);
  GEMM(Ee, op_w, op_b, A, NTOK, 256, 256, 0);                                     // output proj
  // tgt4 = LN(tgt3 + t2d)
  hipLaunchKernelGGL(ln_kernel, dim3(2000), blk, 0, stream, Dd, A, (const float*)nullptr, nc_g, nc_b, Bb);

  // ---- FFN ----
  GEMM(Bb, l1_w, l1_b, Hbuf, NTOK, 1024, 256, 1);                                 // relu
  GEMM(Hbuf, l2_w, l2_b, A, NTOK, 256, 1024, 0);
  // out = LN(tgt4 + ffn)
  hipLaunchKernelGGL(ln_kernel, dim3(2000), blk, 0, stream, Bb, A, (const float*)nullptr, n3_g, n3_b, out);
}

// Round 3
// 805.877 us; speedup vs baseline: 1.4803x; 1.4803x over previous
//
#include <hip/hip_runtime.h>
#include <cmath>

#define NTOK 8000          // B*NQ*NP
#define LV_TOT 17821

typedef __attribute__((ext_vector_type(8))) short short8;
typedef __attribute__((ext_vector_type(4))) float f32x4;

// ---------------- helpers ----------------
__device__ inline unsigned short f2bf(float f) {
  unsigned u = __float_as_uint(f);
  u += 0x7fffu + ((u >> 16) & 1u);          // RNE
  return (unsigned short)(u >> 16);
}
__device__ inline short8 pack8(float4 a, float4 b) {
  short8 r;
  r[0] = (short)f2bf(a.x); r[1] = (short)f2bf(a.y);
  r[2] = (short)f2bf(a.z); r[3] = (short)f2bf(a.w);
  r[4] = (short)f2bf(b.x); r[5] = (short)f2bf(b.y);
  r[6] = (short)f2bf(b.z); r[7] = (short)f2bf(b.w);
  return r;
}
// row = 64B (32 bf16). Swizzle permutes the four 16B slots WITHIN the row:
// slot' = slot ^ (row&3) ^ ((row>>2)&3)  -> 2-way max bank conflict on frag reads (free).
__device__ inline int swz(int row, int ib) {
  int s = ((ib >> 4) ^ (row & 3) ^ ((row >> 2) & 3)) & 3;
  return row * 64 + (s << 4) + (ib & 15);
}

// ---------------- elementwise add (float4) ----------------
__global__ __launch_bounds__(256) void add_kernel(const float* __restrict__ a,
                                                  const float* __restrict__ b,
                                                  float* __restrict__ o, int n4) {
  int i = blockIdx.x * 256 + threadIdx.x;
  if (i < n4) {
    float4 x = reinterpret_cast<const float4*>(a)[i];
    float4 y = reinterpret_cast<const float4*>(b)[i];
    float4 z; z.x = x.x + y.x; z.y = x.y + y.y; z.z = x.z + y.z; z.w = x.w + y.w;
    reinterpret_cast<float4*>(o)[i] = z;
  }
}

// ---------------- MFMA bf16 GEMM: C[M,N] = A[M,K] @ W[N,K]^T (+epilogue) ----------------
// mode 0: +s1(bias); mode 1: relu(+s1); mode 2: relu(acc*s1+s2)  [conv-BN fold]
// conv!=0: A is implicit im2col of x[8000][256]: A[t][kt*256+c] = x[(t/20)*20 + ((t%20)+kt-4 mod 20)][c]
__global__ __launch_bounds__(256) void gemm_mfma_kernel(
    const float* __restrict__ A, const float* __restrict__ W,
    const float* __restrict__ s1, const float* __restrict__ s2,
    float* __restrict__ C, int M, int N, int K, int mode, int conv)
{
  __shared__ __align__(16) char lds[12288];   // A: 128x32 bf16 (8KB) + B: 64x32 bf16 (4KB)
  char* ldsA = lds;
  char* ldsB = lds + 8192;

  const int tid = threadIdx.x;
  const int ar = tid >> 1, ac = (tid & 1) << 4;   // A stage: row, k-elem offset (0/16)
  const int br = tid >> 2, bc = (tid & 3) << 3;   // B stage: row, k-elem offset (0/8/16/24)
  const int arowg = blockIdx.y * 128 + ar;
  const int wrowg = blockIdx.x * 64 + br;
  const bool aval = arowg < M;
  int aseq = 0, anp = 0;
  if (conv) { aseq = arowg / 20; anp = arowg - aseq * 20; }
  const float* wsrc = W + (size_t)wrowg * K + bc;

  const int wv = tid >> 6, l = tid & 63, lr = l & 15, lk = l >> 4;

  f32x4 acc[2][4];
  #pragma unroll
  for (int m = 0; m < 2; ++m)
    #pragma unroll
    for (int n = 0; n < 4; ++n) acc[m][n] = (f32x4){0.f, 0.f, 0.f, 0.f};

  for (int k0 = 0; k0 < K; k0 += 32) {
    float4 a0 = make_float4(0.f,0.f,0.f,0.f), a1 = a0, a2 = a0, a3 = a0;
    if (aval) {
      const float* as;
      if (conv) {
        int kcol = k0 + ac, kt = kcol >> 8, c = kcol & 255;
        int sr = aseq * 20 + ((anp + kt + 16) % 20);
        as = A + (size_t)sr * 256 + c;
      } else {
        as = A + (size_t)arowg * K + k0 + ac;
      }
      a0 = *(const float4*)as;       a1 = *(const float4*)(as + 4);
      a2 = *(const float4*)(as + 8); a3 = *(const float4*)(as + 12);
    }
    float4 w0 = *(const float4*)(wsrc + k0);
    float4 w1 = *(const float4*)(wsrc + k0 + 4);
    __syncthreads();
    *(short8*)(ldsA + swz(ar, ac * 2))      = pack8(a0, a1);
    *(short8*)(ldsA + swz(ar, ac * 2 + 16)) = pack8(a2, a3);
    *(short8*)(ldsB + swz(br, bc * 2))      = pack8(w0, w1);
    __syncthreads();
    short8 af0 = *(short8*)(ldsA + swz(wv * 32 + lr,      lk * 16));
    short8 af1 = *(short8*)(ldsA + swz(wv * 32 + 16 + lr, lk * 16));
    #pragma unroll
    for (int n = 0; n < 4; ++n) {
      short8 bfr = *(short8*)(ldsB + swz(n * 16 + lr, lk * 16));
      acc[0][n] = __builtin_amdgcn_mfma_f32_16x16x32_bf16(af0, bfr, acc[0][n], 0, 0, 0);
      acc[1][n] = __builtin_amdgcn_mfma_f32_16x16x32_bf16(af1, bfr, acc[1][n], 0, 0, 0);
    }
  }
  #pragma unroll
  for (int n = 0; n < 4; ++n) {
    int gcol = blockIdx.x * 64 + n * 16 + lr;
    float sa = s1[gcol];
    float sb = (mode == 2) ? s2[gcol] : 0.f;
    #pragma unroll
    for (int m = 0; m < 2; ++m) {
      #pragma unroll
      for (int i = 0; i < 4; ++i) {
        int grow = blockIdx.y * 128 + wv * 32 + m * 16 + lk * 4 + i;
        if (grow < M) {
          float v = acc[m][n][i];
          v = (mode == 2) ? fmaxf(v * sa + sb, 0.f)
                          : (mode == 1 ? fmaxf(v + sa, 0.f) : v + sa);
          C[(size_t)grow * N + gcol] = v;
        }
      }
    }
  }
}

// ---------------- conv weight reorder: w2[o][k*256+c] = cc_w[o][c][k] ----------------
__global__ __launch_bounds__(256) void convw_kernel(const float* __restrict__ w,
                                                    float* __restrict__ w2) {
  int i = blockIdx.x * 256 + threadIdx.x;   // 256*2304
  int o = i / 2304; int r = i - o * 2304;
  int k = r >> 8, c = r & 255;
  w2[i] = w[(size_t)o * 2304 + c * 9 + k];
}

// ---------------- BN fold: scale = g*rsqrt(v+eps); shift = (cb-m)*scale + b ----------------
__global__ __launch_bounds__(256) void bnfold_kernel(
    const float* __restrict__ cb, const float* __restrict__ g,
    const float* __restrict__ b,  const float* __restrict__ m,
    const float* __restrict__ v,  float* __restrict__ scale,
    float* __restrict__ shift) {
  int o = threadIdx.x;
  float s = g[o] * rsqrtf(v[o] + 1e-5f);
  scale[o] = s;
  shift[o] = (cb[o] - m[o]) * s + b[o];
}

// ---------------- LayerNorm: out = [x3 +] LN(x1 [+ x2]) * g + b ----------------
__global__ __launch_bounds__(256) void ln_kernel(const float* __restrict__ x1,
    const float* __restrict__ x2, const float* __restrict__ x3,
    const float* __restrict__ g, const float* __restrict__ bta,
    float* __restrict__ out)
{
  int wid = threadIdx.x >> 6, lane = threadIdx.x & 63;
  size_t t = (size_t)blockIdx.x * 4 + wid;
  size_t base = t * 256 + (size_t)lane * 4;
  float4 v = *reinterpret_cast<const float4*>(x1 + base);
  if (x2) {
    float4 u = *reinterpret_cast<const float4*>(x2 + base);
    v.x += u.x; v.y += u.y; v.z += u.z; v.w += u.w;
  }
  float s  = v.x + v.y + v.z + v.w;
  float ss = v.x*v.x + v.y*v.y + v.z*v.z + v.w*v.w;
  #pragma unroll
  for (int off = 32; off; off >>= 1) {
    s  += __shfl_xor(s, off, 64);
    ss += __shfl_xor(ss, off, 64);
  }
  float mean = s * (1.0f / 256.0f);
  float var  = ss * (1.0f / 256.0f) - mean * mean;
  float rstd = rsqrtf(var + 1e-5f);
  float4 gv = *reinterpret_cast<const float4*>(g + lane * 4);
  float4 bv = *reinterpret_cast<const float4*>(bta + lane * 4);
  float4 o;
  o.x = (v.x - mean) * rstd * gv.x + bv.x;
  o.y = (v.y - mean) * rstd * gv.y + bv.y;
  o.z = (v.z - mean) * rstd * gv.z + bv.z;
  o.w = (v.w - mean) * rstd * gv.w + bv.w;
  if (x3) {
    float4 u = *reinterpret_cast<const float4*>(x3 + base);
    o.x += u.x; o.y += u.y; o.z += u.z; o.w += u.w;
  }
  *reinterpret_cast<float4*>(out + base) = o;
}

// ---------------- intra attention: 400 seqs of S=20, H=8, DH=32 ----------------
__global__ __launch_bounds__(256) void attn_intra_kernel(
    const float* __restrict__ qp, const float* __restrict__ kp,
    const float* __restrict__ vp, float* __restrict__ outb)
{
  __shared__ float Qs[20][257], Ks[20][257], Vs[20][257];
  int seq = blockIdx.x, t0 = seq * 20;
  for (int idx = threadIdx.x; idx < 20 * 256; idx += 256) {
    int r = idx >> 8, d = idx & 255;
    size_t g = (size_t)(t0 + r) * 256 + d;
    Qs[r][d] = qp[g]; Ks[r][d] = kp[g]; Vs[r][d] = vp[g];
  }
  __syncthreads();
  int h = threadIdx.x >> 5, i = threadIdx.x & 31;
  if (i < 20) {
    const float scale = 0.17677669529663687f;   // 1/sqrt(32)
    float s[20]; float m = -1e30f;
    #pragma unroll
    for (int j = 0; j < 20; ++j) {
      float a = 0.f;
      #pragma unroll
      for (int d = 0; d < 32; ++d) a += Qs[i][h*32+d] * Ks[j][h*32+d];
      a *= scale; s[j] = a; m = fmaxf(m, a);
    }
    float sum = 0.f;
    #pragma unroll
    for (int j = 0; j < 20; ++j) { s[j] = expf(s[j] - m); sum += s[j]; }
    float inv = 1.f / sum;
    #pragma unroll
    for (int d = 0; d < 32; ++d) {
      float o = 0.f;
      #pragma unroll
      for (int j = 0; j < 20; ++j) o += s[j] * Vs[j][h*32+d];
      outb[(size_t)(t0 + i) * 256 + h*32 + d] = o * inv;
    }
  }
}

// ---------------- inter attention: per (b,np,h) block, S=100 over nq ----------------
__global__ __launch_bounds__(128) void attn_inter_kernel(
    const float* __restrict__ qp, const float* __restrict__ kp,
    const float* __restrict__ vp, float* __restrict__ outb)
{
  __shared__ float Ks[100][32], Vs[100][32];
  int blk = blockIdx.x;                 // 0..639
  int h = blk & 7; int sp = blk >> 3; int np = sp % 20; int b = sp / 20;
  for (int idx = threadIdx.x; idx < 100 * 32; idx += 128) {
    int r = idx >> 5, d = idx & 31;
    size_t g = ((size_t)((b * 100 + r) * 20 + np)) * 256 + h*32 + d;
    Ks[r][d] = kp[g]; Vs[r][d] = vp[g];
  }
  __syncthreads();
  int i = threadIdx.x;
  if (i < 100) {
    size_t qbase = ((size_t)((b * 100 + i) * 20 + np)) * 256 + h*32;
    float q[32];
    #pragma unroll
    for (int d4 = 0; d4 < 8; ++d4) {
      float4 v = *reinterpret_cast<const float4*>(qp + qbase + d4*4);
      q[d4*4+0] = v.x; q[d4*4+1] = v.y; q[d4*4+2] = v.z; q[d4*4+3] = v.w;
    }
    const float scale = 0.17677669529663687f;
    float m = -1e30f, l = 0.f, o[32] = {};
    for (int j = 0; j < 100; ++j) {
      float s = 0.f;
      #pragma unroll
      for (int d = 0; d < 32; ++d) s += q[d] * Ks[j][d];
      s *= scale;
      float mn = fmaxf(m, s);
      float f = expf(m - mn), e = expf(s - mn);
      l = l * f + e;
      #pragma unroll
      for (int d = 0; d < 32; ++d) o[d] = o[d] * f + e * Vs[j][d];
      m = mn;
    }
    float inv = 1.f / l;
    #pragma unroll
    for (int d = 0; d < 32; ++d) outb[qbase + d] = o[d] * inv;
  }
}

// ---------------- deformable sampling (softmax over 16 + bilinear gather) ----------------
__global__ __launch_bounds__(256) void deform_kernel(
    const float* __restrict__ value, const float* __restrict__ offs,
    const float* __restrict__ awl, const float* __restrict__ ref,
    float* __restrict__ outb)
{
  int t = blockIdx.x;                       // 0..7999
  int h = threadIdx.x >> 5, dh = threadIdx.x & 31;
  int b = t / 2000;
  float w[16]; float m = -1e30f;
  #pragma unroll
  for (int lp = 0; lp < 16; ++lp) {
    w[lp] = awl[(size_t)t * 128 + h * 16 + lp];
    m = fmaxf(m, w[lp]);
  }
  float sum = 0.f;
  #pragma unroll
  for (int lp = 0; lp < 16; ++lp) { w[lp] = expf(w[lp] - m); sum += w[lp]; }
  float inv = 1.f / sum;
  const int HLs[4] = {100, 50, 25, 13};
  const int WLs[4] = {134, 67, 34, 17};
  const int STs[4] = {0, 13400, 16750, 17600};
  float acc = 0.f;
  #pragma unroll
  for (int l = 0; l < 4; ++l) {
    const int Hl = HLs[l], Wl = WLs[l];
    const float* vb = value + ((size_t)(b * LV_TOT + STs[l])) * 256 + h*32 + dh;
    float rx = ref[(size_t)t * 8 + l * 2 + 0];
    float ry = ref[(size_t)t * 8 + l * 2 + 1];
    #pragma unroll
    for (int p = 0; p < 4; ++p) {
      size_t oi = (size_t)t * 256 + (size_t)(((h*4 + l)*4 + p)*2);
      float ox = offs[oi], oy = offs[oi + 1];
      float x = (rx + ox / (float)Wl) * (float)Wl - 0.5f;
      float y = (ry + oy / (float)Hl) * (float)Hl - 0.5f;
      float x0f = floorf(x), y0f = floorf(y);
      float lx = x - x0f, ly = y - y0f;
      int x0 = (int)x0f, y0 = (int)y0f;
      float wp = w[l*4 + p] * inv;
      float cw00 = (1.f-lx)*(1.f-ly)*wp, cw01 = lx*(1.f-ly)*wp;
      float cw10 = (1.f-lx)*ly*wp,       cw11 = lx*ly*wp;
      if (y0 >= 0 && y0 < Hl) {
        if (x0 >= 0 && x0 < Wl)         acc += cw00 * vb[(size_t)(y0*Wl + x0) * 256];
        if (x0+1 >= 0 && x0+1 < Wl)     acc += cw01 * vb[(size_t)(y0*Wl + x0+1) * 256];
      }
      if (y0+1 >= 0 && y0+1 < Hl) {
        if (x0 >= 0 && x0 < Wl)         acc += cw10 * vb[(size_t)((y0+1)*Wl + x0) * 256];
        if (x0+1 >= 0 && x0+1 < Wl)     acc += cw11 * vb[(size_t)((y0+1)*Wl + x0+1) * 256];
      }
    }
  }
  outb[(size_t)t * 256 + h*32 + dh] = acc;
}

extern "C" void kernel_launch(void* const* d_in, const int* in_sizes, int n_in,
                              void* d_out, int out_size, void* d_ws, size_t ws_size,
                              hipStream_t stream)
{
  const float* tgt  = (const float*)d_in[0];
  const float* qpos = (const float*)d_in[1];
  const float* qpa  = (const float*)d_in[2];
  const float* ref  = (const float*)d_in[3];
  const float* src  = (const float*)d_in[4];
  const float* ia_wi = (const float*)d_in[7];
  const float* ia_bi = (const float*)d_in[8];
  const float* ia_wo = (const float*)d_in[9];
  const float* ia_bo = (const float*)d_in[10];
  const float* cc_w  = (const float*)d_in[11];
  const float* cc_b  = (const float*)d_in[12];
  const float* bn_g  = (const float*)d_in[13];
  const float* bn_b  = (const float*)d_in[14];
  const float* bn_m  = (const float*)d_in[15];
  const float* bn_v  = (const float*)d_in[16];
  const float* ni_g  = (const float*)d_in[17];
  const float* ni_b  = (const float*)d_in[18];
  const float* mf_w  = (const float*)d_in[19];
  const float* mf_b  = (const float*)d_in[20];
  const float* nf_g  = (const float*)d_in[21];
  const float* nf_b  = (const float*)d_in[22];
  const float* in_wi = (const float*)d_in[23];
  const float* in_bi = (const float*)d_in[24];
  const float* in_wo = (const float*)d_in[25];
  const float* in_bo = (const float*)d_in[26];
  const float* nin_g = (const float*)d_in[27];
  const float* nin_b = (const float*)d_in[28];
  const float* so_w  = (const float*)d_in[29];
  const float* so_b  = (const float*)d_in[30];
  const float* aw_w  = (const float*)d_in[31];
  const float* aw_b  = (const float*)d_in[32];
  const float* vp_w  = (const float*)d_in[33];
  const float* vp_b  = (const float*)d_in[34];
  const float* op_w  = (const float*)d_in[35];
  const float* op_b  = (const float*)d_in[36];
  const float* nc_g  = (const float*)d_in[37];
  const float* nc_b  = (const float*)d_in[38];
  const float* l1_w  = (const float*)d_in[39];
  const float* l1_b  = (const float*)d_in[40];
  const float* l2_w  = (const float*)d_in[41];
  const float* l2_b  = (const float*)d_in[42];
  const float* n3_g  = (const float*)d_in[43];
  const float* n3_b  = (const float*)d_in[44];
  float* out = (float*)d_out;

  float* ws = (float*)d_ws;
  const size_t TD = (size_t)NTOK * 256;
  float* A   = ws;
  float* Bb  = ws + TD;
  float* Cc  = ws + 2*TD;
  float* Dd  = ws + 3*TD;
  float* Ee  = ws + 4*TD;
  float* V   = ws + 5*TD;                     // 71284*256
  float* W2  = V + (size_t)71284 * 256;       // 256*2304
  float* bnscale = W2 + (size_t)256 * 2304;
  float* bnshift = bnscale + 256;
  float* Hbuf = V;                            // FFN hidden aliases V (value dead by then)

  dim3 blk(256);
  const int N4 = (int)(TD / 4);

  auto GEMM = [&](const float* Ain, const float* Win, const float* b1, const float* b2,
                  float* Cout, int M_, int N_, int K_, int mode, int conv) {
    dim3 g(N_ / 64, (M_ + 127) / 128);
    hipLaunchKernelGGL(gemm_mfma_kernel, g, blk, 0, stream,
                       Ain, Win, b1, b2, Cout, M_, N_, K_, mode, conv);
  };

  // ---- intra attention ----
  hipLaunchKernelGGL(add_kernel, dim3(2000), blk, 0, stream, tgt, qpos, A, N4);   // q = tgt+pos
  GEMM(A,   ia_wi,             ia_bi,       nullptr, Bb, NTOK, 256, 256, 0, 0);   // qp
  GEMM(A,   ia_wi + 256*256,   ia_bi + 256, nullptr, Cc, NTOK, 256, 256, 0, 0);   // kp
  GEMM(tgt, ia_wi + 512*256,   ia_bi + 512, nullptr, Dd, NTOK, 256, 256, 0, 0);   // vp (value=tgt!)
  hipLaunchKernelGGL(attn_intra_kernel, dim3(400), blk, 0, stream, Bb, Cc, Dd, Ee);
  GEMM(Ee,  ia_wo, ia_bo, nullptr, Bb, NTOK, 256, 256, 0, 0);                     // t

  // ---- circular conv + BN + ReLU on (tgt+pos), as implicit-im2col GEMM ----
  hipLaunchKernelGGL(convw_kernel, dim3(2304), blk, 0, stream, cc_w, W2);
  hipLaunchKernelGGL(bnfold_kernel, dim3(1), blk, 0, stream,
                     cc_b, bn_g, bn_b, bn_m, bn_v, bnscale, bnshift);
  GEMM(A, W2, bnscale, bnshift, Cc, NTOK, 256, 2304, 2, 1);                       // t_cc

  // tgt1 = tgt + LN(t + t_cc)
  hipLaunchKernelGGL(ln_kernel, dim3(2000), blk, 0, stream, Bb, Cc, tgt, ni_g, ni_b, Dd);
  // tgt2 = tgt1 + LN(tgt1 @ mf)
  GEMM(Dd, mf_w, mf_b, nullptr, A, NTOK, 256, 256, 0, 0);
  hipLaunchKernelGGL(ln_kernel, dim3(2000), blk, 0, stream, A, (const float*)nullptr, Dd, nf_g, nf_b, Bb);

  // ---- inter attention ----
  hipLaunchKernelGGL(add_kernel, dim3(2000), blk, 0, stream, Bb, qpa, A, N4);     // q2 = tgt2+anchor
  GEMM(A,  in_wi,           in_bi,       nullptr, Cc, NTOK, 256, 256, 0, 0);      // qp2
  GEMM(A,  in_wi + 256*256, in_bi + 256, nullptr, Dd, NTOK, 256, 256, 0, 0);      // kp2
  GEMM(Bb, in_wi + 512*256, in_bi + 512, nullptr, Ee, NTOK, 256, 256, 0, 0);      // vp2 (value=tgt2)
  hipLaunchKernelGGL(attn_inter_kernel, dim3(640), dim3(128), 0, stream, Cc, Dd, Ee, A);
  GEMM(A, in_wo, in_bo, nullptr, Cc, NTOK, 256, 256, 0, 0);                       // t2
  hipLaunchKernelGGL(ln_kernel, dim3(2000), blk, 0, stream, Bb, Cc, (const float*)nullptr, nin_g, nin_b, Dd);

  // ---- deformable cross-attention ----
  hipLaunchKernelGGL(add_kernel, dim3(2000), blk, 0, stream, Dd, qpos, A, N4);    // qc = tgt3+pos
  GEMM(src, vp_w, vp_b, nullptr, V, 4 * LV_TOT, 256, 256, 0, 0);                  // value
  GEMM(A, so_w, so_b, nullptr, Bb, NTOK, 256, 256, 0, 0);                         // offsets
  GEMM(A, aw_w, aw_b, nullptr, Cc, NTOK, 128, 256, 0, 0);                         // aw logits
  hipLaunchKernelGGL(deform_kernel, dim3(NTOK), blk, 0, stream, V, Bb, Cc, ref, Ee);
  GEMM(Ee, op_w, op_b, nullptr, A, NTOK, 256, 256, 0, 0);                         // output proj
  hipLaunchKernelGGL(ln_kernel, dim3(2000), blk, 0, stream, Dd, A, (const float*)nullptr, nc_g, nc_b, Bb);

  // ---- FFN ----
  GEMM(Bb, l1_w, l1_b, nullptr, Hbuf, NTOK, 1024, 256, 1, 0);
  GEMM(Hbuf, l2_w, l2_b, nullptr, A, NTOK, 256, 1024, 0, 0);
  hipLaunchKernelGGL(ln_kernel, dim3(2000), blk, 0, stream, Bb, A, (const float*)nullptr, n3_g, n3_b, out);
}

// Round 4
// 731.604 us; speedup vs baseline: 1.6306x; 1.1015x over previous
//
#include <hip/hip_runtime.h>
#include <cmath>

#define NTOK 8000          // B*NQ*NP
#define LV_TOT 17821

typedef __attribute__((ext_vector_type(8))) short short8;
typedef __attribute__((ext_vector_type(4))) float f32x4;

// ---------------- helpers ----------------
__device__ inline unsigned short f2bf(float f) {
  unsigned u = __float_as_uint(f);
  u += 0x7fffu + ((u >> 16) & 1u);          // RNE
  return (unsigned short)(u >> 16);
}
__device__ inline short8 pack8(float4 a, float4 b) {
  short8 r;
  r[0] = (short)f2bf(a.x); r[1] = (short)f2bf(a.y);
  r[2] = (short)f2bf(a.z); r[3] = (short)f2bf(a.w);
  r[4] = (short)f2bf(b.x); r[5] = (short)f2bf(b.y);
  r[6] = (short)f2bf(b.z); r[7] = (short)f2bf(b.w);
  return r;
}
// row = 64B (32 bf16). Swizzle permutes the four 16B slots WITHIN the row:
// slot' = slot ^ (row&3) ^ ((row>>2)&3)  -> 2-way max bank conflict (free).
__device__ inline int swz(int row, int ib) {
  int s = ((ib >> 4) ^ (row & 3) ^ ((row >> 2) & 3)) & 3;
  return row * 64 + (s << 4) + (ib & 15);
}

// ---------------- MFMA bf16 GEMM: C[M,N] = (A[+A2])[M,K] @ W[N,K]^T (+epilogue) ----------
// mode 0: +s1(bias); mode 1: relu(+s1); mode 2: relu(acc*s1+s2)  [conv-BN fold]
// conv!=0: A is implicit im2col of x[8000][256]: col kt*256+c -> x[(t/20)*20+((t%20)+kt-4 mod 20)][c]
// A2: optional elementwise add to A (same layout/gather); applied only when blockIdx.x*64 < addLimit.
__global__ __launch_bounds__(256) void gemm_mfma_kernel(
    const float* __restrict__ A, const float* __restrict__ A2,
    const float* __restrict__ W,
    const float* __restrict__ s1, const float* __restrict__ s2,
    float* __restrict__ C, int M, int N, int K, int mode, int conv, int addLimit)
{
  __shared__ __align__(16) char lds[12288];   // A: 128x32 bf16 (8KB) + B: 64x32 bf16 (4KB)
  char* ldsA = lds;
  char* ldsB = lds + 8192;

  const int tid = threadIdx.x;
  const int ar = tid >> 1, ac = (tid & 1) << 4;   // A stage: row, k-elem offset (0/16)
  const int br = tid >> 2, bc = (tid & 3) << 3;   // B stage: row, k-elem offset
  const int arowg = blockIdx.y * 128 + ar;
  const int wrowg = blockIdx.x * 64 + br;
  const bool aval = arowg < M;
  const bool doadd = (A2 != nullptr) && ((int)blockIdx.x * 64 < addLimit);
  int aseq = 0, anp = 0;
  if (conv) { aseq = arowg / 20; anp = arowg - aseq * 20; }
  const float* wsrc = W + (size_t)wrowg * K + bc;

  const int wv = tid >> 6, l = tid & 63, lr = l & 15, lk = l >> 4;

  f32x4 acc[2][4];
  #pragma unroll
  for (int m = 0; m < 2; ++m)
    #pragma unroll
    for (int n = 0; n < 4; ++n) acc[m][n] = (f32x4){0.f, 0.f, 0.f, 0.f};

  for (int k0 = 0; k0 < K; k0 += 32) {
    float4 a0 = make_float4(0.f,0.f,0.f,0.f), a1 = a0, a2 = a0, a3 = a0;
    if (aval) {
      size_t off;
      if (conv) {
        int kcol = k0 + ac, kt = kcol >> 8, c = kcol & 255;
        int sr = aseq * 20 + ((anp + kt + 16) % 20);
        off = (size_t)sr * 256 + c;
      } else {
        off = (size_t)arowg * K + k0 + ac;
      }
      const float* as = A + off;
      a0 = *(const float4*)as;       a1 = *(const float4*)(as + 4);
      a2 = *(const float4*)(as + 8); a3 = *(const float4*)(as + 12);
      if (doadd) {
        const float* as2 = A2 + off;
        float4 b0 = *(const float4*)as2;       float4 b1 = *(const float4*)(as2 + 4);
        float4 b2 = *(const float4*)(as2 + 8); float4 b3 = *(const float4*)(as2 + 12);
        a0.x+=b0.x; a0.y+=b0.y; a0.z+=b0.z; a0.w+=b0.w;
        a1.x+=b1.x; a1.y+=b1.y; a1.z+=b1.z; a1.w+=b1.w;
        a2.x+=b2.x; a2.y+=b2.y; a2.z+=b2.z; a2.w+=b2.w;
        a3.x+=b3.x; a3.y+=b3.y; a3.z+=b3.z; a3.w+=b3.w;
      }
    }
    float4 w0 = *(const float4*)(wsrc + k0);
    float4 w1 = *(const float4*)(wsrc + k0 + 4);
    __syncthreads();
    *(short8*)(ldsA + swz(ar, ac * 2))      = pack8(a0, a1);
    *(short8*)(ldsA + swz(ar, ac * 2 + 16)) = pack8(a2, a3);
    *(short8*)(ldsB + swz(br, bc * 2))      = pack8(w0, w1);
    __syncthreads();
    short8 af0 = *(short8*)(ldsA + swz(wv * 32 + lr,      lk * 16));
    short8 af1 = *(short8*)(ldsA + swz(wv * 32 + 16 + lr, lk * 16));
    #pragma unroll
    for (int n = 0; n < 4; ++n) {
      short8 bfr = *(short8*)(ldsB + swz(n * 16 + lr, lk * 16));
      acc[0][n] = __builtin_amdgcn_mfma_f32_16x16x32_bf16(af0, bfr, acc[0][n], 0, 0, 0);
      acc[1][n] = __builtin_amdgcn_mfma_f32_16x16x32_bf16(af1, bfr, acc[1][n], 0, 0, 0);
    }
  }
  #pragma unroll
  for (int n = 0; n < 4; ++n) {
    int gcol = blockIdx.x * 64 + n * 16 + lr;
    float sa = s1[gcol];
    float sb = (mode == 2) ? s2[gcol] : 0.f;
    #pragma unroll
    for (int m = 0; m < 2; ++m) {
      #pragma unroll
      for (int i = 0; i < 4; ++i) {
        int grow = blockIdx.y * 128 + wv * 32 + m * 16 + lk * 4 + i;
        if (grow < M) {
          float v = acc[m][n][i];
          v = (mode == 2) ? fmaxf(v * sa + sb, 0.f)
                          : (mode == 1 ? fmaxf(v + sa, 0.f) : v + sa);
          C[(size_t)grow * N + gcol] = v;
        }
      }
    }
  }
}

// ---------------- conv weight reorder: w2[o][k*256+c] = cc_w[o][c][k] ----------------
__global__ __launch_bounds__(256) void convw_kernel(const float* __restrict__ w,
                                                    float* __restrict__ w2) {
  int i = blockIdx.x * 256 + threadIdx.x;   // 256*2304
  int o = i / 2304; int r = i - o * 2304;
  int k = r >> 8, c = r & 255;
  w2[i] = w[(size_t)o * 2304 + c * 9 + k];
}

// ---------------- BN fold + offs/aw weight concat ----------------
__global__ __launch_bounds__(256) void bnfold_kernel(
    const float* __restrict__ cb, const float* __restrict__ g,
    const float* __restrict__ b,  const float* __restrict__ m,
    const float* __restrict__ v,  float* __restrict__ scale,
    float* __restrict__ shift) {
  int o = threadIdx.x;
  float s = g[o] * rsqrtf(v[o] + 1e-5f);
  scale[o] = s;
  shift[o] = (cb[o] - m[o]) * s + b[o];
}
__global__ __launch_bounds__(256) void wcat_kernel(
    const float* __restrict__ so_w, const float* __restrict__ so_b,
    const float* __restrict__ aw_w, const float* __restrict__ aw_b,
    float* __restrict__ wsb, float* __restrict__ bsb) {
  int r = blockIdx.x, c = threadIdx.x;
  wsb[(size_t)r * 256 + c] = (r < 256) ? so_w[(size_t)r * 256 + c]
                                       : aw_w[(size_t)(r - 256) * 256 + c];
  if (c == 0) bsb[r] = (r < 256) ? so_b[r] : aw_b[r - 256];
}

// ---------------- LayerNorm: out = [x3 +] LN(x1 [+ x2]) * g + b ----------------
__global__ __launch_bounds__(256) void ln_kernel(const float* __restrict__ x1,
    const float* __restrict__ x2, const float* __restrict__ x3,
    const float* __restrict__ g, const float* __restrict__ bta,
    float* __restrict__ out)
{
  int wid = threadIdx.x >> 6, lane = threadIdx.x & 63;
  size_t t = (size_t)blockIdx.x * 4 + wid;
  size_t base = t * 256 + (size_t)lane * 4;
  float4 v = *reinterpret_cast<const float4*>(x1 + base);
  if (x2) {
    float4 u = *reinterpret_cast<const float4*>(x2 + base);
    v.x += u.x; v.y += u.y; v.z += u.z; v.w += u.w;
  }
  float s  = v.x + v.y + v.z + v.w;
  float ss = v.x*v.x + v.y*v.y + v.z*v.z + v.w*v.w;
  #pragma unroll
  for (int off = 32; off; off >>= 1) {
    s  += __shfl_xor(s, off, 64);
    ss += __shfl_xor(ss, off, 64);
  }
  float mean = s * (1.0f / 256.0f);
  float var  = ss * (1.0f / 256.0f) - mean * mean;
  float rstd = rsqrtf(var + 1e-5f);
  float4 gv = *reinterpret_cast<const float4*>(g + lane * 4);
  float4 bv = *reinterpret_cast<const float4*>(bta + lane * 4);
  float4 o;
  o.x = (v.x - mean) * rstd * gv.x + bv.x;
  o.y = (v.y - mean) * rstd * gv.y + bv.y;
  o.z = (v.z - mean) * rstd * gv.z + bv.z;
  o.w = (v.w - mean) * rstd * gv.w + bv.w;
  if (x3) {
    float4 u = *reinterpret_cast<const float4*>(x3 + base);
    o.x += u.x; o.y += u.y; o.z += u.z; o.w += u.w;
  }
  *reinterpret_cast<float4*>(out + base) = o;
}

// ---------------- intra attention: 400 seqs of S=20, H=8, DH=32; qkv strided 768 ----------------
__global__ __launch_bounds__(256) void attn_intra_kernel(
    const float* __restrict__ qkv, float* __restrict__ outb)
{
  __shared__ float Qs[20][257], Ks[20][257], Vs[20][257];
  int seq = blockIdx.x, t0 = seq * 20;
  for (int idx = threadIdx.x; idx < 20 * 256; idx += 256) {
    int r = idx >> 8, d = idx & 255;
    size_t g = (size_t)(t0 + r) * 768 + d;
    Qs[r][d] = qkv[g]; Ks[r][d] = qkv[g + 256]; Vs[r][d] = qkv[g + 512];
  }
  __syncthreads();
  int h = threadIdx.x >> 5, i = threadIdx.x & 31;
  if (i < 20) {
    const float scale = 0.17677669529663687f;   // 1/sqrt(32)
    float s[20]; float m = -1e30f;
    #pragma unroll
    for (int j = 0; j < 20; ++j) {
      float a = 0.f;
      #pragma unroll
      for (int d = 0; d < 32; ++d) a += Qs[i][h*32+d] * Ks[j][h*32+d];
      a *= scale; s[j] = a; m = fmaxf(m, a);
    }
    float sum = 0.f;
    #pragma unroll
    for (int j = 0; j < 20; ++j) { s[j] = expf(s[j] - m); sum += s[j]; }
    float inv = 1.f / sum;
    #pragma unroll
    for (int d = 0; d < 32; ++d) {
      float o = 0.f;
      #pragma unroll
      for (int j = 0; j < 20; ++j) o += s[j] * Vs[j][h*32+d];
      outb[(size_t)(t0 + i) * 256 + h*32 + d] = o * inv;
    }
  }
}

// ---------------- inter attention: per (b,np,h) block, S=100 over nq; qkv strided 768 ----------------
__global__ __launch_bounds__(128) void attn_inter_kernel(
    const float* __restrict__ qkv, float* __restrict__ outb)
{
  __shared__ float Ks[100][32], Vs[100][32];
  int blk = blockIdx.x;                 // 0..639
  int h = blk & 7; int sp = blk >> 3; int np = sp % 20; int b = sp / 20;
  for (int idx = threadIdx.x; idx < 100 * 32; idx += 128) {
    int r = idx >> 5, d = idx & 31;
    size_t g = ((size_t)((b * 100 + r) * 20 + np)) * 768 + h*32 + d;
    Ks[r][d] = qkv[g + 256]; Vs[r][d] = qkv[g + 512];
  }
  __syncthreads();
  int i = threadIdx.x;
  if (i < 100) {
    size_t tok = (size_t)(b * 100 + i) * 20 + np;
    size_t qbase = tok * 768 + h*32;
    float q[32];
    #pragma unroll
    for (int d4 = 0; d4 < 8; ++d4) {
      float4 v = *reinterpret_cast<const float4*>(qkv + qbase + d4*4);
      q[d4*4+0] = v.x; q[d4*4+1] = v.y; q[d4*4+2] = v.z; q[d4*4+3] = v.w;
    }
    const float scale = 0.17677669529663687f;
    float m = -1e30f, l = 0.f, o[32] = {};
    for (int j = 0; j < 100; ++j) {
      float s = 0.f;
      #pragma unroll
      for (int d = 0; d < 32; ++d) s += q[d] * Ks[j][d];
      s *= scale;
      float mn = fmaxf(m, s);
      float f = expf(m - mn), e = expf(s - mn);
      l = l * f + e;
      #pragma unroll
      for (int d = 0; d < 32; ++d) o[d] = o[d] * f + e * Vs[j][d];
      m = mn;
    }
    float inv = 1.f / l;
    #pragma unroll
    for (int d = 0; d < 32; ++d) outb[tok * 256 + h*32 + d] = o[d] * inv;
  }
}

// ---------------- deformable sampling: 1 wave/token, 8 lanes/head, float4 taps ----------------
__global__ __launch_bounds__(256) void deform_kernel(
    const float* __restrict__ value, const float* __restrict__ oa,
    const float* __restrict__ ref, float* __restrict__ outb)
{
  int t = blockIdx.x * 4 + (threadIdx.x >> 6);   // token
  int lane = threadIdx.x & 63;
  int h = lane >> 3, q4 = (lane & 7) << 2;
  int b = t / 2000;
  const float* awp  = oa + (size_t)t * 384 + 256 + h * 16;
  const float* offp = oa + (size_t)t * 384 + h * 32;
  float w[16]; float m = -1e30f;
  #pragma unroll
  for (int lp = 0; lp < 16; ++lp) { w[lp] = awp[lp]; m = fmaxf(m, w[lp]); }
  float sum = 0.f;
  #pragma unroll
  for (int lp = 0; lp < 16; ++lp) { w[lp] = expf(w[lp] - m); sum += w[lp]; }
  float inv = 1.f / sum;
  const int HLs[4] = {100, 50, 25, 13};
  const int WLs[4] = {134, 67, 34, 17};
  const int STs[4] = {0, 13400, 16750, 17600};
  float4 acc = make_float4(0.f, 0.f, 0.f, 0.f);
  #pragma unroll
  for (int l = 0; l < 4; ++l) {
    const int Hl = HLs[l], Wl = WLs[l];
    const float* vb = value + ((size_t)(b * LV_TOT + STs[l])) * 256 + h*32 + q4;
    float rx = ref[(size_t)t * 8 + l * 2 + 0];
    float ry = ref[(size_t)t * 8 + l * 2 + 1];
    #pragma unroll
    for (int p = 0; p < 4; ++p) {
      float ox = offp[(l*4 + p)*2], oy = offp[(l*4 + p)*2 + 1];
      float x = (rx + ox / (float)Wl) * (float)Wl - 0.5f;
      float y = (ry + oy / (float)Hl) * (float)Hl - 0.5f;
      float x0f = floorf(x), y0f = floorf(y);
      float lx = x - x0f, ly = y - y0f;
      int x0 = (int)x0f, y0 = (int)y0f;
      float wp = w[l*4 + p] * inv;
      float cw00 = (1.f-lx)*(1.f-ly)*wp, cw01 = lx*(1.f-ly)*wp;
      float cw10 = (1.f-lx)*ly*wp,       cw11 = lx*ly*wp;
      bool yv0 = (y0 >= 0) & (y0 < Hl), yv1 = (y0+1 >= 0) & (y0+1 < Hl);
      bool xv0 = (x0 >= 0) & (x0 < Wl), xv1 = (x0+1 >= 0) & (x0+1 < Wl);
      if (yv0 & xv0) { float4 v = *(const float4*)(vb + (size_t)(y0*Wl + x0) * 256);
        acc.x += cw00*v.x; acc.y += cw00*v.y; acc.z += cw00*v.z; acc.w += cw00*v.w; }
      if (yv0 & xv1) { float4 v = *(const float4*)(vb + (size_t)(y0*Wl + x0+1) * 256);
        acc.x += cw01*v.x; acc.y += cw01*v.y; acc.z += cw01*v.z; acc.w += cw01*v.w; }
      if (yv1 & xv0) { float4 v = *(const float4*)(vb + (size_t)((y0+1)*Wl + x0) * 256);
        acc.x += cw10*v.x; acc.y += cw10*v.y; acc.z += cw10*v.z; acc.w += cw10*v.w; }
      if (yv1 & xv1) { float4 v = *(const float4*)(vb + (size_t)((y0+1)*Wl + x0+1) * 256);
        acc.x += cw11*v.x; acc.y += cw11*v.y; acc.z += cw11*v.z; acc.w += cw11*v.w; }
    }
  }
  *(float4*)(outb + (size_t)t * 256 + h*32 + q4) = acc;
}

extern "C" void kernel_launch(void* const* d_in, const int* in_sizes, int n_in,
                              void* d_out, int out_size, void* d_ws, size_t ws_size,
                              hipStream_t stream)
{
  const float* tgt  = (const float*)d_in[0];
  const float* qpos = (const float*)d_in[1];
  const float* qpa  = (const float*)d_in[2];
  const float* ref  = (const float*)d_in[3];
  const float* src  = (const float*)d_in[4];
  const float* ia_wi = (const float*)d_in[7];
  const float* ia_bi = (const float*)d_in[8];
  const float* ia_wo = (const float*)d_in[9];
  const float* ia_bo = (const float*)d_in[10];
  const float* cc_w  = (const float*)d_in[11];
  const float* cc_b  = (const float*)d_in[12];
  const float* bn_g  = (const float*)d_in[13];
  const float* bn_b  = (const float*)d_in[14];
  const float* bn_m  = (const float*)d_in[15];
  const float* bn_v  = (const float*)d_in[16];
  const float* ni_g  = (const float*)d_in[17];
  const float* ni_b  = (const float*)d_in[18];
  const float* mf_w  = (const float*)d_in[19];
  const float* mf_b  = (const float*)d_in[20];
  const float* nf_g  = (const float*)d_in[21];
  const float* nf_b  = (const float*)d_in[22];
  const float* in_wi = (const float*)d_in[23];
  const float* in_bi = (const float*)d_in[24];
  const float* in_wo = (const float*)d_in[25];
  const float* in_bo = (const float*)d_in[26];
  const float* nin_g = (const float*)d_in[27];
  const float* nin_b = (const float*)d_in[28];
  const float* so_w  = (const float*)d_in[29];
  const float* so_b  = (const float*)d_in[30];
  const float* aw_w  = (const float*)d_in[31];
  const float* aw_b  = (const float*)d_in[32];
  const float* vp_w  = (const float*)d_in[33];
  const float* vp_b  = (const float*)d_in[34];
  const float* op_w  = (const float*)d_in[35];
  const float* op_b  = (const float*)d_in[36];
  const float* nc_g  = (const float*)d_in[37];
  const float* nc_b  = (const float*)d_in[38];
  const float* l1_w  = (const float*)d_in[39];
  const float* l1_b  = (const float*)d_in[40];
  const float* l2_w  = (const float*)d_in[41];
  const float* l2_b  = (const float*)d_in[42];
  const float* n3_g  = (const float*)d_in[43];
  const float* n3_b  = (const float*)d_in[44];
  float* out = (float*)d_out;

  float* ws = (float*)d_ws;
  const size_t TD  = (size_t)NTOK * 256;
  const size_t QVs = (size_t)71284 * 256;       // value region; aliases qkv buf & FFN hidden
  float* QV = ws;
  float* T1 = ws + QVs;
  float* T2 = T1 + TD;
  float* T3 = T2 + TD;
  float* T4 = T3 + TD;
  float* W2 = T4 + TD;                          // 256*2304
  float* WSB = W2 + (size_t)256 * 2304;         // 384*256
  float* BSB = WSB + (size_t)384 * 256;         // 384
  float* bnscale = BSB + 384;
  float* bnshift = bnscale + 256;

  dim3 blk(256);
  auto GEMM = [&](const float* Ain, const float* Aadd, const float* Win,
                  const float* b1, const float* b2, float* Cout,
                  int M_, int N_, int K_, int mode, int conv, int addLim) {
    dim3 g(N_ / 64, (M_ + 127) / 128);
    hipLaunchKernelGGL(gemm_mfma_kernel, g, blk, 0, stream,
                       Ain, Aadd, Win, b1, b2, Cout, M_, N_, K_, mode, conv, addLim);
  };

  // ---- intra attention: one N=768 QKV GEMM (q,k from tgt+qpos; v from tgt) ----
  GEMM(tgt, qpos, ia_wi, ia_bi, nullptr, QV, NTOK, 768, 256, 0, 0, 512);
  hipLaunchKernelGGL(attn_intra_kernel, dim3(400), blk, 0, stream, QV, T1);
  GEMM(T1, nullptr, ia_wo, ia_bo, nullptr, T2, NTOK, 256, 256, 0, 0, 0);          // t

  // ---- circular conv + BN + ReLU on (tgt+qpos) as implicit-im2col GEMM ----
  hipLaunchKernelGGL(convw_kernel, dim3(2304), blk, 0, stream, cc_w, W2);
  hipLaunchKernelGGL(bnfold_kernel, dim3(1), blk, 0, stream,
                     cc_b, bn_g, bn_b, bn_m, bn_v, bnscale, bnshift);
  GEMM(tgt, qpos, W2, bnscale, bnshift, T3, NTOK, 256, 2304, 2, 1, 256);          // t_cc

  // tgt1 = tgt + LN(t + t_cc)
  hipLaunchKernelGGL(ln_kernel, dim3(2000), blk, 0, stream, T2, T3, tgt, ni_g, ni_b, T4);
  // tgt2 = tgt1 + LN(tgt1 @ mf)
  GEMM(T4, nullptr, mf_w, mf_b, nullptr, T1, NTOK, 256, 256, 0, 0, 0);
  hipLaunchKernelGGL(ln_kernel, dim3(2000), blk, 0, stream, T1, (const float*)nullptr, T4, nf_g, nf_b, T2);

  // ---- inter attention: one N=768 QKV GEMM (q,k from tgt2+qpa; v from tgt2) ----
  GEMM(T2, qpa, in_wi, in_bi, nullptr, QV, NTOK, 768, 256, 0, 0, 512);
  hipLaunchKernelGGL(attn_inter_kernel, dim3(640), dim3(128), 0, stream, QV, T1);
  GEMM(T1, nullptr, in_wo, in_bo, nullptr, T3, NTOK, 256, 256, 0, 0, 0);          // t2
  // tgt3 = LN(tgt2 + t2)
  hipLaunchKernelGGL(ln_kernel, dim3(2000), blk, 0, stream, T2, T3, (const float*)nullptr, nin_g, nin_b, T4);

  // ---- deformable cross-attention ----
  hipLaunchKernelGGL(wcat_kernel, dim3(384), blk, 0, stream, so_w, so_b, aw_w, aw_b, WSB, BSB);
  GEMM(src, nullptr, vp_w, vp_b, nullptr, QV, 4 * LV_TOT, 256, 256, 0, 0, 0);     // value (QV region)
  GEMM(T4, qpos, WSB, BSB, nullptr, T1, NTOK, 384, 256, 0, 0, 384);               // offs|aw -> OA (T1..T2)
  hipLaunchKernelGGL(deform_kernel, dim3(2000), blk, 0, stream, QV, T1, ref, T3);
  GEMM(T3, nullptr, op_w, op_b, nullptr, T2, NTOK, 256, 256, 0, 0, 0);            // output proj
  // tgt4 = LN(tgt3 + t2d)
  hipLaunchKernelGGL(ln_kernel, dim3(2000), blk, 0, stream, T4, T2, (const float*)nullptr, nc_g, nc_b, T1);

  // ---- FFN ----
  GEMM(T1, nullptr, l1_w, l1_b, nullptr, QV, NTOK, 1024, 256, 1, 0, 0);           // hidden (QV region)
  GEMM(QV, nullptr, l2_w, l2_b, nullptr, T2, NTOK, 256, 1024, 0, 0, 0);
  hipLaunchKernelGGL(ln_kernel, dim3(2000), blk, 0, stream, T1, T2, (const float*)nullptr, n3_g, n3_b, out);
}

// Round 5
// 679.854 us; speedup vs baseline: 1.7547x; 1.0761x over previous
//
#include <hip/hip_runtime.h>
#include <cmath>

#define NTOK 8000          // B*NQ*NP
#define LV_TOT 17821

typedef __attribute__((ext_vector_type(8))) short short8;
typedef __attribute__((ext_vector_type(4))) float f32x4;

// ---------------- helpers ----------------
__device__ inline unsigned short f2bf(float f) {
  unsigned u = __float_as_uint(f);
  u += 0x7fffu + ((u >> 16) & 1u);          // RNE
  return (unsigned short)(u >> 16);
}
__device__ inline short8 pack8(float4 a, float4 b) {
  short8 r;
  r[0] = (short)f2bf(a.x); r[1] = (short)f2bf(a.y);
  r[2] = (short)f2bf(a.z); r[3] = (short)f2bf(a.w);
  r[4] = (short)f2bf(b.x); r[5] = (short)f2bf(b.y);
  r[6] = (short)f2bf(b.z); r[7] = (short)f2bf(b.w);
  return r;
}
// row = 64B (32 bf16). Swizzle permutes the four 16B slots WITHIN the row:
// slot' = slot ^ (row&3) ^ ((row>>2)&3)  -> 2-way max bank conflict (free).
__device__ inline int swz(int row, int ib) {
  int s = ((ib >> 4) ^ (row & 3) ^ ((row >> 2) & 3)) & 3;
  return row * 64 + (s << 4) + (ib & 15);
}

// ---------------- MFMA bf16 GEMM: C[M,N] = (A[+A2])[M,K] @ W[N,K]^T (+epilogue) ----------
// mode 0: +s1(bias); mode 1: relu(+s1); mode 2: relu(acc*s1+s2)  [conv-BN fold]
// conv!=0: A is implicit im2col of x[8000][256]: col kt*256+c -> x[(t/20)*20+((t%20)+kt-4 mod 20)][c]
// A2: optional elementwise add to A (same layout/gather); applied only when bx*64 < addLimit.
// 1D grid; XCD-bijective chunked swizzle (col-fastest within chunk) so column-blocks
// sharing an A row-panel land on the SAME XCD -> A is fetched from HBM once, L2-served after.
__global__ __launch_bounds__(256) void gemm_mfma_kernel(
    const float* __restrict__ A, const float* __restrict__ A2,
    const float* __restrict__ W,
    const float* __restrict__ s1, const float* __restrict__ s2,
    float* __restrict__ C, int M, int N, int K, int mode, int conv, int addLimit,
    int nbx)
{
  __shared__ __align__(16) char lds[12288];   // A: 128x32 bf16 (8KB) + B: 64x32 bf16 (4KB)
  char* ldsA = lds;
  char* ldsB = lds + 8192;

  // XCD-bijective swizzle (m204): hw round-robins consecutive blockIdx across 8 XCDs;
  // give each XCD a contiguous col-fastest work range. Bijective for any grid size.
  const int nb = gridDim.x;
  {
  }
  const int q8 = nb >> 3, r8 = nb & 7;
  const int xcd = blockIdx.x & 7, pos = blockIdx.x >> 3;
  const int Lw = xcd * q8 + (xcd < r8 ? xcd : r8) + pos;
  const int bx = Lw % nbx;
  const int by = Lw / nbx;

  const int tid = threadIdx.x;
  const int ar = tid >> 1, ac = (tid & 1) << 4;   // A stage: row, k-elem offset (0/16)
  const int br = tid >> 2, bc = (tid & 3) << 3;   // B stage: row, k-elem offset
  const int arowg = by * 128 + ar;
  const int wrowg = bx * 64 + br;
  const bool aval = arowg < M;
  const bool doadd = (A2 != nullptr) && (bx * 64 < addLimit);
  int aseq = 0, anp = 0;
  if (conv) { aseq = arowg / 20; anp = arowg - aseq * 20; }
  const float* wsrc = W + (size_t)wrowg * K + bc;

  const int wv = tid >> 6, l = tid & 63, lr = l & 15, lk = l >> 4;

  f32x4 acc[2][4];
  #pragma unroll
  for (int m = 0; m < 2; ++m)
    #pragma unroll
    for (int n = 0; n < 4; ++n) acc[m][n] = (f32x4){0.f, 0.f, 0.f, 0.f};

  for (int k0 = 0; k0 < K; k0 += 32) {
    float4 a0 = make_float4(0.f,0.f,0.f,0.f), a1 = a0, a2 = a0, a3 = a0;
    if (aval) {
      size_t off;
      if (conv) {
        int kcol = k0 + ac, kt = kcol >> 8, c = kcol & 255;
        int sr = aseq * 20 + ((anp + kt + 16) % 20);
        off = (size_t)sr * 256 + c;
      } else {
        off = (size_t)arowg * K + k0 + ac;
      }
      const float* as = A + off;
      a0 = *(const float4*)as;       a1 = *(const float4*)(as + 4);
      a2 = *(const float4*)(as + 8); a3 = *(const float4*)(as + 12);
      if (doadd) {
        const float* as2 = A2 + off;
        float4 b0 = *(const float4*)as2;       float4 b1 = *(const float4*)(as2 + 4);
        float4 b2 = *(const float4*)(as2 + 8); float4 b3 = *(const float4*)(as2 + 12);
        a0.x+=b0.x; a0.y+=b0.y; a0.z+=b0.z; a0.w+=b0.w;
        a1.x+=b1.x; a1.y+=b1.y; a1.z+=b1.z; a1.w+=b1.w;
        a2.x+=b2.x; a2.y+=b2.y; a2.z+=b2.z; a2.w+=b2.w;
        a3.x+=b3.x; a3.y+=b3.y; a3.z+=b3.z; a3.w+=b3.w;
      }
    }
    float4 w0 = *(const float4*)(wsrc + k0);
    float4 w1 = *(const float4*)(wsrc + k0 + 4);
    __syncthreads();
    *(short8*)(ldsA + swz(ar, ac * 2))      = pack8(a0, a1);
    *(short8*)(ldsA + swz(ar, ac * 2 + 16)) = pack8(a2, a3);
    *(short8*)(ldsB + swz(br, bc * 2))      = pack8(w0, w1);
    __syncthreads();
    short8 af0 = *(short8*)(ldsA + swz(wv * 32 + lr,      lk * 16));
    short8 af1 = *(short8*)(ldsA + swz(wv * 32 + 16 + lr, lk * 16));
    #pragma unroll
    for (int n = 0; n < 4; ++n) {
      short8 bfr = *(short8*)(ldsB + swz(n * 16 + lr, lk * 16));
      acc[0][n] = __builtin_amdgcn_mfma_f32_16x16x32_bf16(af0, bfr, acc[0][n], 0, 0, 0);
      acc[1][n] = __builtin_amdgcn_mfma_f32_16x16x32_bf16(af1, bfr, acc[1][n], 0, 0, 0);
    }
  }
  #pragma unroll
  for (int n = 0; n < 4; ++n) {
    int gcol = bx * 64 + n * 16 + lr;
    float sa = s1[gcol];
    float sb = (mode == 2) ? s2[gcol] : 0.f;
    #pragma unroll
    for (int m = 0; m < 2; ++m) {
      #pragma unroll
      for (int i = 0; i < 4; ++i) {
        int grow = by * 128 + wv * 32 + m * 16 + lk * 4 + i;
        if (grow < M) {
          float v = acc[m][n][i];
          v = (mode == 2) ? fmaxf(v * sa + sb, 0.f)
                          : (mode == 1 ? fmaxf(v + sa, 0.f) : v + sa);
          C[(size_t)grow * N + gcol] = v;
        }
      }
    }
  }
}

// ---------------- conv weight reorder: w2[o][k*256+c] = cc_w[o][c][k] ----------------
__global__ __launch_bounds__(256) void convw_kernel(const float* __restrict__ w,
                                                    float* __restrict__ w2) {
  int i = blockIdx.x * 256 + threadIdx.x;   // 256*2304
  int o = i / 2304; int r = i - o * 2304;
  int k = r >> 8, c = r & 255;
  w2[i] = w[(size_t)o * 2304 + c * 9 + k];
}

// ---------------- BN fold + offs/aw weight concat ----------------
__global__ __launch_bounds__(256) void bnfold_kernel(
    const float* __restrict__ cb, const float* __restrict__ g,
    const float* __restrict__ b,  const float* __restrict__ m,
    const float* __restrict__ v,  float* __restrict__ scale,
    float* __restrict__ shift) {
  int o = threadIdx.x;
  float s = g[o] * rsqrtf(v[o] + 1e-5f);
  scale[o] = s;
  shift[o] = (cb[o] - m[o]) * s + b[o];
}
__global__ __launch_bounds__(256) void wcat_kernel(
    const float* __restrict__ so_w, const float* __restrict__ so_b,
    const float* __restrict__ aw_w, const float* __restrict__ aw_b,
    float* __restrict__ wsb, float* __restrict__ bsb) {
  int r = blockIdx.x, c = threadIdx.x;
  wsb[(size_t)r * 256 + c] = (r < 256) ? so_w[(size_t)r * 256 + c]
                                       : aw_w[(size_t)(r - 256) * 256 + c];
  if (c == 0) bsb[r] = (r < 256) ? so_b[r] : aw_b[r - 256];
}

// ---------------- LayerNorm: out = [x3 +] LN(x1 [+ x2]) * g + b ----------------
__global__ __launch_bounds__(256) void ln_kernel(const float* __restrict__ x1,
    const float* __restrict__ x2, const float* __restrict__ x3,
    const float* __restrict__ g, const float* __restrict__ bta,
    float* __restrict__ out)
{
  int wid = threadIdx.x >> 6, lane = threadIdx.x & 63;
  size_t t = (size_t)blockIdx.x * 4 + wid;
  size_t base = t * 256 + (size_t)lane * 4;
  float4 v = *reinterpret_cast<const float4*>(x1 + base);
  if (x2) {
    float4 u = *reinterpret_cast<const float4*>(x2 + base);
    v.x += u.x; v.y += u.y; v.z += u.z; v.w += u.w;
  }
  float s  = v.x + v.y + v.z + v.w;
  float ss = v.x*v.x + v.y*v.y + v.z*v.z + v.w*v.w;
  #pragma unroll
  for (int off = 32; off; off >>= 1) {
    s  += __shfl_xor(s, off, 64);
    ss += __shfl_xor(ss, off, 64);
  }
  float mean = s * (1.0f / 256.0f);
  float var  = ss * (1.0f / 256.0f) - mean * mean;
  float rstd = rsqrtf(var + 1e-5f);
  float4 gv = *reinterpret_cast<const float4*>(g + lane * 4);
  float4 bv = *reinterpret_cast<const float4*>(bta + lane * 4);
  float4 o;
  o.x = (v.x - mean) * rstd * gv.x + bv.x;
  o.y = (v.y - mean) * rstd * gv.y + bv.y;
  o.z = (v.z - mean) * rstd * gv.z + bv.z;
  o.w = (v.w - mean) * rstd * gv.w + bv.w;
  if (x3) {
    float4 u = *reinterpret_cast<const float4*>(x3 + base);
    o.x += u.x; o.y += u.y; o.z += u.z; o.w += u.w;
  }
  *reinterpret_cast<float4*>(out + base) = o;
}

// ---------------- intra attention: 400 seqs of S=20, H=8, DH=32; qkv strided 768 ----------------
__global__ __launch_bounds__(256) void attn_intra_kernel(
    const float* __restrict__ qkv, float* __restrict__ outb)
{
  __shared__ float Qs[20][257], Ks[20][257], Vs[20][257];
  int seq = blockIdx.x, t0 = seq * 20;
  for (int idx = threadIdx.x; idx < 20 * 256; idx += 256) {
    int r = idx >> 8, d = idx & 255;
    size_t g = (size_t)(t0 + r) * 768 + d;
    Qs[r][d] = qkv[g]; Ks[r][d] = qkv[g + 256]; Vs[r][d] = qkv[g + 512];
  }
  __syncthreads();
  int h = threadIdx.x >> 5, i = threadIdx.x & 31;
  if (i < 20) {
    const float scale = 0.17677669529663687f;   // 1/sqrt(32)
    float s[20]; float m = -1e30f;
    #pragma unroll
    for (int j = 0; j < 20; ++j) {
      float a = 0.f;
      #pragma unroll
      for (int d = 0; d < 32; ++d) a += Qs[i][h*32+d] * Ks[j][h*32+d];
      a *= scale; s[j] = a; m = fmaxf(m, a);
    }
    float sum = 0.f;
    #pragma unroll
    for (int j = 0; j < 20; ++j) { s[j] = expf(s[j] - m); sum += s[j]; }
    float inv = 1.f / sum;
    #pragma unroll
    for (int d = 0; d < 32; ++d) {
      float o = 0.f;
      #pragma unroll
      for (int j = 0; j < 20; ++j) o += s[j] * Vs[j][h*32+d];
      outb[(size_t)(t0 + i) * 256 + h*32 + d] = o * inv;
    }
  }
}

// ---------------- inter attention: per (b,np,h) block, S=100 over nq; qkv strided 768 ----------------
__global__ __launch_bounds__(128) void attn_inter_kernel(
    const float* __restrict__ qkv, float* __restrict__ outb)
{
  __shared__ float Ks[100][32], Vs[100][32];
  int blk = blockIdx.x;                 // 0..639
  int h = blk & 7; int sp = blk >> 3; int np = sp % 20; int b = sp / 20;
  for (int idx = threadIdx.x; idx < 100 * 32; idx += 128) {
    int r = idx >> 5, d = idx & 31;
    size_t g = ((size_t)((b * 100 + r) * 20 + np)) * 768 + h*32 + d;
    Ks[r][d] = qkv[g + 256]; Vs[r][d] = qkv[g + 512];
  }
  __syncthreads();
  int i = threadIdx.x;
  if (i < 100) {
    size_t tok = (size_t)(b * 100 + i) * 20 + np;
    size_t qbase = tok * 768 + h*32;
    float q[32];
    #pragma unroll
    for (int d4 = 0; d4 < 8; ++d4) {
      float4 v = *reinterpret_cast<const float4*>(qkv + qbase + d4*4);
      q[d4*4+0] = v.x; q[d4*4+1] = v.y; q[d4*4+2] = v.z; q[d4*4+3] = v.w;
    }
    const float scale = 0.17677669529663687f;
    float m = -1e30f, l = 0.f, o[32] = {};
    for (int j = 0; j < 100; ++j) {
      float s = 0.f;
      #pragma unroll
      for (int d = 0; d < 32; ++d) s += q[d] * Ks[j][d];
      s *= scale;
      float mn = fmaxf(m, s);
      float f = expf(m - mn), e = expf(s - mn);
      l = l * f + e;
      #pragma unroll
      for (int d = 0; d < 32; ++d) o[d] = o[d] * f + e * Vs[j][d];
      m = mn;
    }
    float inv = 1.f / l;
    #pragma unroll
    for (int d = 0; d < 32; ++d) outb[tok * 256 + h*32 + d] = o[d] * inv;
  }
}

// ---------------- deformable sampling: 1 wave/token, 8 lanes/head, float4 taps ----------------
__global__ __launch_bounds__(256) void deform_kernel(
    const float* __restrict__ value, const float* __restrict__ oa,
    const float* __restrict__ ref, float* __restrict__ outb)
{
  int t = blockIdx.x * 4 + (threadIdx.x >> 6);   // token
  int lane = threadIdx.x & 63;
  int h = lane >> 3, q4 = (lane & 7) << 2;
  int b = t / 2000;
  const float* awp  = oa + (size_t)t * 384 + 256 + h * 16;
  const float* offp = oa + (size_t)t * 384 + h * 32;
  float w[16]; float m = -1e30f;
  #pragma unroll
  for (int lp = 0; lp < 16; ++lp) { w[lp] = awp[lp]; m = fmaxf(m, w[lp]); }
  float sum = 0.f;
  #pragma unroll
  for (int lp = 0; lp < 16; ++lp) { w[lp] = expf(w[lp] - m); sum += w[lp]; }
  float inv = 1.f / sum;
  const int HLs[4] = {100, 50, 25, 13};
  const int WLs[4] = {134, 67, 34, 17};
  const int STs[4] = {0, 13400, 16750, 17600};
  float4 acc = make_float4(0.f, 0.f, 0.f, 0.f);
  #pragma unroll
  for (int l = 0; l < 4; ++l) {
    const int Hl = HLs[l], Wl = WLs[l];
    const float* vb = value + ((size_t)(b * LV_TOT + STs[l])) * 256 + h*32 + q4;
    float rx = ref[(size_t)t * 8 + l * 2 + 0];
    float ry = ref[(size_t)t * 8 + l * 2 + 1];
    #pragma unroll
    for (int p = 0; p < 4; ++p) {
      float ox = offp[(l*4 + p)*2], oy = offp[(l*4 + p)*2 + 1];
      float x = (rx + ox / (float)Wl) * (float)Wl - 0.5f;
      float y = (ry + oy / (float)Hl) * (float)Hl - 0.5f;
      float x0f = floorf(x), y0f = floorf(y);
      float lx = x - x0f, ly = y - y0f;
      int x0 = (int)x0f, y0 = (int)y0f;
      float wp = w[l*4 + p] * inv;
      float cw00 = (1.f-lx)*(1.f-ly)*wp, cw01 = lx*(1.f-ly)*wp;
      float cw10 = (1.f-lx)*ly*wp,       cw11 = lx*ly*wp;
      bool yv0 = (y0 >= 0) & (y0 < Hl), yv1 = (y0+1 >= 0) & (y0+1 < Hl);
      bool xv0 = (x0 >= 0) & (x0 < Wl), xv1 = (x0+1 >= 0) & (x0+1 < Wl);
      if (yv0 & xv0) { float4 v = *(const float4*)(vb + (size_t)(y0*Wl + x0) * 256);
        acc.x += cw00*v.x; acc.y += cw00*v.y; acc.z += cw00*v.z; acc.w += cw00*v.w; }
      if (yv0 & xv1) { float4 v = *(const float4*)(vb + (size_t)(y0*Wl + x0+1) * 256);
        acc.x += cw01*v.x; acc.y += cw01*v.y; acc.z += cw01*v.z; acc.w += cw01*v.w; }
      if (yv1 & xv0) { float4 v = *(const float4*)(vb + (size_t)((y0+1)*Wl + x0) * 256);
        acc.x += cw10*v.x; acc.y += cw10*v.y; acc.z += cw10*v.z; acc.w += cw10*v.w; }
      if (yv1 & xv1) { float4 v = *(const float4*)(vb + (size_t)((y0+1)*Wl + x0+1) * 256);
        acc.x += cw11*v.x; acc.y += cw11*v.y; acc.z += cw11*v.z; acc.w += cw11*v.w; }
    }
  }
  *(float4*)(outb + (size_t)t * 256 + h*32 + q4) = acc;
}

extern "C" void kernel_launch(void* const* d_in, const int* in_sizes, int n_in,
                              void* d_out, int out_size, void* d_ws, size_t ws_size,
                              hipStream_t stream)
{
  const float* tgt  = (const float*)d_in[0];
  const float* qpos = (const float*)d_in[1];
  const float* qpa  = (const float*)d_in[2];
  const float* ref  = (const float*)d_in[3];
  const float* src  = (const float*)d_in[4];
  const float* ia_wi = (const float*)d_in[7];
  const float* ia_bi = (const float*)d_in[8];
  const float* ia_wo = (const float*)d_in[9];
  const float* ia_bo = (const float*)d_in[10];
  const float* cc_w  = (const float*)d_in[11];
  const float* cc_b  = (const float*)d_in[12];
  const float* bn_g  = (const float*)d_in[13];
  const float* bn_b  = (const float*)d_in[14];
  const float* bn_m  = (const float*)d_in[15];
  const float* bn_v  = (const float*)d_in[16];
  const float* ni_g  = (const float*)d_in[17];
  const float* ni_b  = (const float*)d_in[18];
  const float* mf_w  = (const float*)d_in[19];
  const float* mf_b  = (const float*)d_in[20];
  const float* nf_g  = (const float*)d_in[21];
  const float* nf_b  = (const float*)d_in[22];
  const float* in_wi = (const float*)d_in[23];
  const float* in_bi = (const float*)d_in[24];
  const float* in_wo = (const float*)d_in[25];
  const float* in_bo = (const float*)d_in[26];
  const float* nin_g = (const float*)d_in[27];
  const float* nin_b = (const float*)d_in[28];
  const float* so_w  = (const float*)d_in[29];
  const float* so_b  = (const float*)d_in[30];
  const float* aw_w  = (const float*)d_in[31];
  const float* aw_b  = (const float*)d_in[32];
  const float* vp_w  = (const float*)d_in[33];
  const float* vp_b  = (const float*)d_in[34];
  const float* op_w  = (const float*)d_in[35];
  const float* op_b  = (const float*)d_in[36];
  const float* nc_g  = (const float*)d_in[37];
  const float* nc_b  = (const float*)d_in[38];
  const float* l1_w  = (const float*)d_in[39];
  const float* l1_b  = (const float*)d_in[40];
  const float* l2_w  = (const float*)d_in[41];
  const float* l2_b  = (const float*)d_in[42];
  const float* n3_g  = (const float*)d_in[43];
  const float* n3_b  = (const float*)d_in[44];
  float* out = (float*)d_out;

  float* ws = (float*)d_ws;
  const size_t TD  = (size_t)NTOK * 256;
  const size_t QVs = (size_t)71284 * 256;       // value region; aliases qkv buf & FFN hidden
  float* QV = ws;
  float* T1 = ws + QVs;
  float* T2 = T1 + TD;
  float* T3 = T2 + TD;
  float* T4 = T3 + TD;
  float* W2 = T4 + TD;                          // 256*2304
  float* WSB = W2 + (size_t)256 * 2304;         // 384*256
  float* BSB = WSB + (size_t)384 * 256;         // 384
  float* bnscale = BSB + 384;
  float* bnshift = bnscale + 256;

  dim3 blk(256);
  auto GEMM = [&](const float* Ain, const float* Aadd, const float* Win,
                  const float* b1, const float* b2, float* Cout,
                  int M_, int N_, int K_, int mode, int conv, int addLim) {
    int nbx = N_ / 64, nby = (M_ + 127) / 128;
    hipLaunchKernelGGL(gemm_mfma_kernel, dim3(nbx * nby), blk, 0, stream,
                       Ain, Aadd, Win, b1, b2, Cout, M_, N_, K_, mode, conv, addLim, nbx);
  };

  // ---- intra attention: one N=768 QKV GEMM (q,k from tgt+qpos; v from tgt) ----
  GEMM(tgt, qpos, ia_wi, ia_bi, nullptr, QV, NTOK, 768, 256, 0, 0, 512);
  hipLaunchKernelGGL(attn_intra_kernel, dim3(400), blk, 0, stream, QV, T1);
  GEMM(T1, nullptr, ia_wo, ia_bo, nullptr, T2, NTOK, 256, 256, 0, 0, 0);          // t

  // ---- circular conv + BN + ReLU on (tgt+qpos) as implicit-im2col GEMM ----
  hipLaunchKernelGGL(convw_kernel, dim3(2304), blk, 0, stream, cc_w, W2);
  hipLaunchKernelGGL(bnfold_kernel, dim3(1), blk, 0, stream,
                     cc_b, bn_g, bn_b, bn_m, bn_v, bnscale, bnshift);
  GEMM(tgt, qpos, W2, bnscale, bnshift, T3, NTOK, 256, 2304, 2, 1, 256);          // t_cc

  // tgt1 = tgt + LN(t + t_cc)
  hipLaunchKernelGGL(ln_kernel, dim3(2000), blk, 0, stream, T2, T3, tgt, ni_g, ni_b, T4);
  // tgt2 = tgt1 + LN(tgt1 @ mf)
  GEMM(T4, nullptr, mf_w, mf_b, nullptr, T1, NTOK, 256, 256, 0, 0, 0);
  hipLaunchKernelGGL(ln_kernel, dim3(2000), blk, 0, stream, T1, (const float*)nullptr, T4, nf_g, nf_b, T2);

  // ---- inter attention: one N=768 QKV GEMM (q,k from tgt2+qpa; v from tgt2) ----
  GEMM(T2, qpa, in_wi, in_bi, nullptr, QV, NTOK, 768, 256, 0, 0, 512);
  hipLaunchKernelGGL(attn_inter_kernel, dim3(640), dim3(128), 0, stream, QV, T1);
  GEMM(T1, nullptr, in_wo, in_bo, nullptr, T3, NTOK, 256, 256, 0, 0, 0);          // t2
  // tgt3 = LN(tgt2 + t2)
  hipLaunchKernelGGL(ln_kernel, dim3(2000), blk, 0, stream, T2, T3, (const float*)nullptr, nin_g, nin_b, T4);

  // ---- deformable cross-attention ----
  hipLaunchKernelGGL(wcat_kernel, dim3(384), blk, 0, stream, so_w, so_b, aw_w, aw_b, WSB, BSB);
  GEMM(src, nullptr, vp_w, vp_b, nullptr, QV, 4 * LV_TOT, 256, 256, 0, 0, 0);     // value (QV region)
  GEMM(T4, qpos, WSB, BSB, nullptr, T1, NTOK, 384, 256, 0, 0, 384);               // offs|aw -> OA (T1..T2)
  hipLaunchKernelGGL(deform_kernel, dim3(2000), blk, 0, stream, QV, T1, ref, T3);
  GEMM(T3, nullptr, op_w, op_b, nullptr, T2, NTOK, 256, 256, 0, 0, 0);            // output proj
  // tgt4 = LN(tgt3 + t2d)
  hipLaunchKernelGGL(ln_kernel, dim3(2000), blk, 0, stream, T4, T2, (const float*)nullptr, nc_g, nc_b, T1);

  // ---- FFN ----
  GEMM(T1, nullptr, l1_w, l1_b, nullptr, QV, NTOK, 1024, 256, 1, 0, 0);           // hidden (QV region)
  GEMM(QV, nullptr, l2_w, l2_b, nullptr, T2, NTOK, 256, 1024, 0, 0, 0);
  hipLaunchKernelGGL(ln_kernel, dim3(2000), blk, 0, stream, T1, T2, (const float*)nullptr, n3_g, n3_b, out);
}